// Round 5
// baseline (329.725 us; speedup 1.0000x reference)
//
#include <hip/hip_runtime.h>
#include <hip/hip_bf16.h>
#include <math.h>

// Problem constants
#define LL 4096
#define DD 1024
#define NN 16
#define KK 4
#define BB 2
#define MM (BB * LL)   // 8192
#define NC 64          // scan chunks
#define LC 64          // chunk length (NC*LC == LL)

typedef unsigned short ushort_t;
typedef short s16x8 __attribute__((ext_vector_type(8)));
typedef float f32x4 __attribute__((ext_vector_type(4)));
typedef unsigned int u32;

__device__ __forceinline__ ushort_t f2bf(float f) {
  __hip_bfloat16 h = __float2bfloat16(f);
  return *reinterpret_cast<ushort_t*>(&h);
}
__device__ __forceinline__ float bf2f(ushort_t u) {
  union { u32 i; float f; } c;
  c.i = ((u32)u) << 16;
  return c.f;
}

// ---------------------------------------------------------------------------
// bf16 MFMA GEMM, B-transposed: C[M,N] = A[M,K] @ BT[N,K]^T + bias, K=1024.
// 128x128 tile, BK=32, 256 threads (4 waves, 2x2), 16x16x32 MFMA,
// global_load_lds width-16 staging (m97 structure). BF16OUT selects output
// dtype: bf16 for the in-proj intermediate, f32 for the final output.
// ---------------------------------------------------------------------------
template <bool BF16OUT>
__global__ __launch_bounds__(256) void gemm_bt_mfma(
    const ushort_t* __restrict__ A,   // [M,K] bf16
    const ushort_t* __restrict__ BT,  // [N,K] bf16
    const float* __restrict__ bias,
    void* __restrict__ Cv, int N) {
  constexpr int K = 1024;
  __shared__ ushort_t As[128 * 32];
  __shared__ ushort_t Bs[128 * 32];

  const int tid = threadIdx.x;
  const int lane = tid & 63;
  const int w = tid >> 6;            // wave 0..3
  const int wm = w & 1, wn = w >> 1; // 2x2 wave grid over the 128x128 tile
  const int row0 = blockIdx.y * 128;
  const int col0 = blockIdx.x * 128;

  const int lrow = lane >> 2;        // 0..15
  const int lk = (lane & 3) * 8;     // 0,8,16,24

  f32x4 acc[4][4];
#pragma unroll
  for (int i = 0; i < 4; ++i)
#pragma unroll
    for (int j = 0; j < 4; ++j) acc[i][j] = (f32x4){0.f, 0.f, 0.f, 0.f};

  const int frow = lane & 15;
  const int quad = lane >> 4;

  for (int k0 = 0; k0 < K; k0 += 32) {
#pragma unroll
    for (int it = 0; it < 2; ++it) {
      int r = it * 64 + w * 16;
      __builtin_amdgcn_global_load_lds(
          (const __attribute__((address_space(1))) u32*)(A + (size_t)(row0 + r + lrow) * K + k0 + lk),
          (__attribute__((address_space(3))) u32*)(As + r * 32), 16, 0, 0);
      __builtin_amdgcn_global_load_lds(
          (const __attribute__((address_space(1))) u32*)(BT + (size_t)(col0 + r + lrow) * K + k0 + lk),
          (__attribute__((address_space(3))) u32*)(Bs + r * 32), 16, 0, 0);
    }
    __syncthreads();

    s16x8 af[4], bf[4];
#pragma unroll
    for (int mi = 0; mi < 4; ++mi)
      af[mi] = *(const s16x8*)&As[(wm * 64 + mi * 16 + frow) * 32 + quad * 8];
#pragma unroll
    for (int ni = 0; ni < 4; ++ni)
      bf[ni] = *(const s16x8*)&Bs[(wn * 64 + ni * 16 + frow) * 32 + quad * 8];
#pragma unroll
    for (int mi = 0; mi < 4; ++mi)
#pragma unroll
      for (int ni = 0; ni < 4; ++ni)
        acc[mi][ni] = __builtin_amdgcn_mfma_f32_16x16x32_bf16(
            af[mi], bf[ni], acc[mi][ni], 0, 0, 0);
    __syncthreads();
  }

  // Epilogue: C/D layout col=lane&15, row=quad*4+reg
#pragma unroll
  for (int mi = 0; mi < 4; ++mi) {
#pragma unroll
    for (int ni = 0; ni < 4; ++ni) {
      int col = col0 + wn * 64 + ni * 16 + frow;
      float b = bias[col];
#pragma unroll
      for (int r = 0; r < 4; ++r) {
        int row = row0 + wm * 64 + mi * 16 + quad * 4 + r;
        if constexpr (BF16OUT)
          ((ushort_t*)Cv)[(size_t)row * N + col] = f2bf(acc[mi][ni][r] + b);
        else
          ((float*)Cv)[(size_t)row * N + col] = acc[mi][ni][r] + b;
      }
    }
  }
}

// ---------------------------------------------------------------------------
// BC projection, bf16 MFMA: BC[M,32] = XCb[M,1024] @ WxT[32,1024]^T + b_x.
// ---------------------------------------------------------------------------
__global__ __launch_bounds__(128) void bc_mfma_k(
    const ushort_t* __restrict__ A,   // XCb [M,1024]
    const ushort_t* __restrict__ BT,  // WxT [32,1024]
    const float* __restrict__ bias,   // [32]
    float* __restrict__ C) {          // BC [M,32]
  constexpr int K = 1024;
  __shared__ ushort_t As[32 * 32];
  __shared__ ushort_t Bs[32 * 32];

  const int tid = threadIdx.x;
  const int lane = tid & 63;
  const int w = tid >> 6;
  const int row0 = blockIdx.x * 32;
  const int lrow = lane >> 2;
  const int lk = (lane & 3) * 8;
  const int frow = lane & 15;
  const int quad = lane >> 4;

  f32x4 acc[2];
  acc[0] = (f32x4){0.f, 0.f, 0.f, 0.f};
  acc[1] = (f32x4){0.f, 0.f, 0.f, 0.f};

  for (int k0 = 0; k0 < K; k0 += 32) {
    __builtin_amdgcn_global_load_lds(
        (const __attribute__((address_space(1))) u32*)(A + (size_t)(row0 + w * 16 + lrow) * K + k0 + lk),
        (__attribute__((address_space(3))) u32*)(As + (w * 16) * 32), 16, 0, 0);
    __builtin_amdgcn_global_load_lds(
        (const __attribute__((address_space(1))) u32*)(BT + (size_t)(w * 16 + lrow) * K + k0 + lk),
        (__attribute__((address_space(3))) u32*)(Bs + (w * 16) * 32), 16, 0, 0);
    __syncthreads();

    s16x8 af = *(const s16x8*)&As[(w * 16 + frow) * 32 + quad * 8];
    s16x8 bf0 = *(const s16x8*)&Bs[(frow)*32 + quad * 8];
    s16x8 bf1 = *(const s16x8*)&Bs[(16 + frow) * 32 + quad * 8];
    acc[0] = __builtin_amdgcn_mfma_f32_16x16x32_bf16(af, bf0, acc[0], 0, 0, 0);
    acc[1] = __builtin_amdgcn_mfma_f32_16x16x32_bf16(af, bf1, acc[1], 0, 0, 0);
    __syncthreads();
  }

#pragma unroll
  for (int ni = 0; ni < 2; ++ni) {
    int col = ni * 16 + frow;
    float b = bias[col];
#pragma unroll
    for (int r = 0; r < 4; ++r) {
      int row = row0 + w * 16 + quad * 4 + r;
      C[(size_t)row * 32 + col] = acc[ni][r] + b;
    }
  }
}

// ---------------------------------------------------------------------------
// fp32 -> bf16 cast (4 floats/thread) + zero the 32-float final_state region.
// ---------------------------------------------------------------------------
__global__ __launch_bounds__(256) void cast_bf16_k(
    const float* __restrict__ src, ushort_t* __restrict__ dst,
    float* __restrict__ fs) {
  if (blockIdx.x == 0 && threadIdx.x < 32) fs[threadIdx.x] = 0.f;
  int i = blockIdx.x * 256 + threadIdx.x;
  float4 v = ((const float4*)src)[i];
  ushort4 o;
  o.x = f2bf(v.x); o.y = f2bf(v.y); o.z = f2bf(v.z); o.w = f2bf(v.w);
  ((ushort4*)dst)[i] = o;
}

// ---------------------------------------------------------------------------
// All three weight transposes in one launch (z selects the weight).
// W [K,N] fp32 -> WT [N,K] bf16.
// ---------------------------------------------------------------------------
__global__ void transpose_cast3_k(
    const float* __restrict__ W_in, const float* __restrict__ W_out,
    const float* __restrict__ W_x, ushort_t* __restrict__ WinT,
    ushort_t* __restrict__ WoutT, ushort_t* __restrict__ WxT) {
  constexpr int K = 1024;
  const float* W;
  ushort_t* WT;
  int N;
  if (blockIdx.z == 0) {
    W = W_in; WT = WinT; N = 2048;
  } else if (blockIdx.z == 1) {
    if (blockIdx.x >= 32) return;
    W = W_out; WT = WoutT; N = 1024;
  } else {
    if (blockIdx.x >= 1) return;
    W = W_x; WT = WxT; N = 32;
  }
  __shared__ float t[32][33];
  int nb = blockIdx.x * 32, kb = blockIdx.y * 32;
  int tx = threadIdx.x, ty = threadIdx.y;  // (32,8)
#pragma unroll
  for (int i = 0; i < 32; i += 8)
    t[ty + i][tx] = W[(size_t)(kb + ty + i) * N + nb + tx];
  __syncthreads();
#pragma unroll
  for (int i = 0; i < 32; i += 8)
    WT[(size_t)(nb + ty + i) * K + kb + tx] = f2bf(t[tx][ty + i]);
}

// ---------------------------------------------------------------------------
// Depthwise causal conv (left pad K-1) + SiLU, all-bf16 I/O.
// XGb [M,2048] bf16 -> XCb [M,1024] bf16. 8 d per thread, 16B loads/stores.
// ---------------------------------------------------------------------------
__global__ __launch_bounds__(256) void conv_silu_k(
    const ushort_t* __restrict__ XGb, const float* __restrict__ conv_w,
    const float* __restrict__ conv_b, ushort_t* __restrict__ XCb) {
  int gid = blockIdx.x * 256 + threadIdx.x;  // over M*128
  int m = gid >> 7;
  int d0 = (gid & 127) * 8;
  int l = m & (LL - 1);

  float acc[8];
#pragma unroll
  for (int j = 0; j < 8; ++j) acc[j] = conv_b[d0 + j];
#pragma unroll
  for (int k = 0; k < KK; ++k) {
    int li = l + k - (KK - 1);
    if (li < 0) continue;
    s16x8 v = *(const s16x8*)(XGb + (size_t)(m + k - (KK - 1)) * 2048 + d0);
#pragma unroll
    for (int j = 0; j < 8; ++j)
      acc[j] += bf2f((ushort_t)v[j]) * conv_w[(d0 + j) * KK + k];
  }
  ushort_t o[8];
#pragma unroll
  for (int j = 0; j < 8; ++j) {
    float s = acc[j] / (1.f + __expf(-acc[j]));
    o[j] = f2bf(s);
  }
  *(s16x8*)(XCb + (size_t)m * DD + d0) = *(const s16x8*)o;
}

// ---------------------------------------------------------------------------
// Scan phase 1: per-chunk local scan from h=0; store chunk end-state S.
// Grid (B, NC, D/128); 64 threads, 2 d per thread (ushort2 xc loads).
// ---------------------------------------------------------------------------
__global__ __launch_bounds__(64) void scan_local_k(
    const ushort_t* __restrict__ XCb, const float* __restrict__ BC,
    const float* __restrict__ A_log, float* __restrict__ S) {
  const int b = blockIdx.x, c = blockIdx.y;
  const int tid = threadIdx.x;
  const int d0 = blockIdx.z * 128 + tid * 2;
  const int t0 = c * LC;
  const size_t rowb = (size_t)b * LL;

  __shared__ float bcs[LC * 32];
  {
    const float4* src = (const float4*)(BC + (rowb + t0) * 32);
    float4* dst = (float4*)bcs;
#pragma unroll
    for (int i = 0; i < 8; ++i) dst[tid + i * 64] = src[tid + i * 64];
  }

  float a0[NN], a1[NN], h0[NN], h1[NN];
#pragma unroll
  for (int n = 0; n < NN; ++n) {
    a0[n] = expf(-expf(A_log[d0 * NN + n]));
    a1[n] = expf(-expf(A_log[(d0 + 1) * NN + n]));
    h0[n] = 0.f;
    h1[n] = 0.f;
  }
  __syncthreads();

  const ushort_t* xp = XCb + (rowb + t0) * DD + d0;
  u32 xw = *(const u32*)xp;
  for (int t = 0; t < LC; ++t) {
    u32 xw_n = (t + 1 < LC) ? *(const u32*)(xp + (size_t)(t + 1) * DD) : 0u;
    float x0 = bf2f((ushort_t)(xw & 0xffff));
    float x1 = bf2f((ushort_t)(xw >> 16));
    const float* bp = bcs + t * 32;
#pragma unroll
    for (int n = 0; n < NN; ++n) {
      float bv = bp[n];
      h0[n] = a0[n] * h0[n] + x0 * bv;
      h1[n] = a1[n] * h1[n] + x1 * bv;
    }
    xw = xw_n;
  }
  float* sp = S + (((size_t)(b * NC + c)) * DD + d0) * NN;
#pragma unroll
  for (int n = 0; n < NN; ++n) sp[n] = h0[n];
#pragma unroll
  for (int n = 0; n < NN; ++n) sp[NN + n] = h1[n];
}

// ---------------------------------------------------------------------------
// Scan phase 2: sequential carry over chunks (S -> H0 in place) + fs mean.
// ---------------------------------------------------------------------------
__global__ __launch_bounds__(256) void scan_carry_k(
    float* __restrict__ S, const float* __restrict__ A_log,
    float* __restrict__ fs) {
  const int idx = blockIdx.x * 256 + threadIdx.x;
  const int n = idx & (NN - 1);
  const int d = (idx / NN) & (DD - 1);
  const int b = idx / (NN * DD);

  const float aLC = expf(-(float)LC * expf(A_log[d * NN + n]));
  float h = 0.f;
  for (int c = 0; c < NC; ++c) {
    size_t off = (((size_t)(b * NC + c)) * DD + d) * NN + n;
    float s = S[off];
    S[off] = h;
    h = aLC * h + s;
  }
  __shared__ float red[256];
  red[threadIdx.x] = h * (1.f / (float)DD);
  __syncthreads();
  if (threadIdx.x < NN) {
    float sum = 0.f;
#pragma unroll
    for (int i = 0; i < 16; ++i) sum += red[i * NN + threadIdx.x];
    atomicAdd(&fs[b * NN + threadIdx.x], sum);
  }
}

// ---------------------------------------------------------------------------
// Scan phase 3: replay from H0, y*silu(gate) -> Y1b bf16. 2 d per thread.
// ---------------------------------------------------------------------------
__global__ __launch_bounds__(64) void scan_final_k(
    const ushort_t* __restrict__ XCb, const ushort_t* __restrict__ XGb,
    const float* __restrict__ BC, const float* __restrict__ A_log,
    const float* __restrict__ D_param, const float* __restrict__ H0,
    ushort_t* __restrict__ Y1b) {
  const int b = blockIdx.x, c = blockIdx.y;
  const int tid = threadIdx.x;
  const int d0 = blockIdx.z * 128 + tid * 2;
  const int t0 = c * LC;
  const size_t rowb = (size_t)b * LL;

  __shared__ float bcs[LC * 32];
  {
    const float4* src = (const float4*)(BC + (rowb + t0) * 32);
    float4* dst = (float4*)bcs;
#pragma unroll
    for (int i = 0; i < 8; ++i) dst[tid + i * 64] = src[tid + i * 64];
  }

  float a0[NN], a1[NN], h0[NN], h1[NN];
  const float* hp = H0 + (((size_t)(b * NC + c)) * DD + d0) * NN;
#pragma unroll
  for (int n = 0; n < NN; ++n) {
    a0[n] = expf(-expf(A_log[d0 * NN + n]));
    a1[n] = expf(-expf(A_log[(d0 + 1) * NN + n]));
    h0[n] = hp[n];
    h1[n] = hp[NN + n];
  }
  const float Dp0 = D_param[d0], Dp1 = D_param[d0 + 1];
  __syncthreads();

  const ushort_t* xp = XCb + (rowb + t0) * DD + d0;
  const ushort_t* gp = XGb + (rowb + t0) * 2048 + DD + d0;
  ushort_t* yp = Y1b + (rowb + t0) * DD + d0;
  u32 xw = *(const u32*)xp;
  u32 gw = *(const u32*)gp;
  for (int t = 0; t < LC; ++t) {
    u32 xw_n = 0u, gw_n = 0u;
    if (t + 1 < LC) {
      xw_n = *(const u32*)(xp + (size_t)(t + 1) * DD);
      gw_n = *(const u32*)(gp + (size_t)(t + 1) * 2048);
    }
    float x0 = bf2f((ushort_t)(xw & 0xffff));
    float x1 = bf2f((ushort_t)(xw >> 16));
    float g0 = bf2f((ushort_t)(gw & 0xffff));
    float g1 = bf2f((ushort_t)(gw >> 16));
    float y0 = Dp0 * x0, y1 = Dp1 * x1;
    const float* bp = bcs + t * 32;
#pragma unroll
    for (int n = 0; n < NN; ++n) {
      float bv = bp[n], cv = bp[16 + n];
      h0[n] = a0[n] * h0[n] + x0 * bv;
      h1[n] = a1[n] * h1[n] + x1 * bv;
      y0 += cv * h0[n];
      y1 += cv * h1[n];
    }
    float sg0 = g0 / (1.f + __expf(-g0));
    float sg1 = g1 / (1.f + __expf(-g1));
    u32 outw = (u32)f2bf(y0 * sg0) | ((u32)f2bf(y1 * sg1) << 16);
    *(u32*)(yp + (size_t)t * DD) = outw;
    xw = xw_n;
    gw = gw_n;
  }
}

// ---------------------------------------------------------------------------
extern "C" void kernel_launch(void* const* d_in, const int* in_sizes, int n_in,
                              void* d_out, int out_size, void* d_ws,
                              size_t ws_size, hipStream_t stream) {
  const float* x = (const float*)d_in[0];
  const float* W_in = (const float*)d_in[1];
  const float* b_in = (const float*)d_in[2];
  const float* conv_w = (const float*)d_in[3];
  const float* conv_b = (const float*)d_in[4];
  const float* W_x = (const float*)d_in[5];
  const float* b_x = (const float*)d_in[6];
  const float* A_log = (const float*)d_in[7];
  const float* D_param = (const float*)d_in[8];
  const float* W_out = (const float*)d_in[9];
  const float* b_out = (const float*)d_in[10];
  float* out = (float*)d_out;
  float* fs = out + (size_t)MM * DD;

  // ws layout: f32 regions then bf16 regions (all 16B-aligned)
  float* BC = (float*)d_ws;                    // [8192*32] f32
  float* S = BC + (size_t)MM * 32;             // [2*64*1024*16] f32
  ushort_t* Xb = (ushort_t*)(S + (size_t)BB * NC * DD * NN);  // [8192*1024]
  ushort_t* XGb = Xb + (size_t)MM * DD;        // [8192*2048] bf16
  ushort_t* XCb = XGb + (size_t)MM * 2048;     // [8192*1024] bf16
  ushort_t* Y1b = XCb + (size_t)MM * DD;       // [8192*1024] bf16
  ushort_t* WinT = Y1b + (size_t)MM * DD;      // [2048*1024] bf16
  ushort_t* WoutT = WinT + (size_t)2048 * DD;  // [1024*1024] bf16
  ushort_t* WxT = WoutT + (size_t)DD * DD;     // [32*1024] bf16

  dim3 blk(256);
  // 1. cast x -> bf16 (+ zero final_state accumulator)
  cast_bf16_k<<<dim3((MM * DD) / 1024), blk, 0, stream>>>(x, Xb, fs);
  // 2. all weight transposes
  transpose_cast3_k<<<dim3(64, 32, 3), dim3(32, 8), 0, stream>>>(
      W_in, W_out, W_x, WinT, WoutT, WxT);
  // 3. in-proj (bf16 MFMA, bf16 out): XGb = x @ W_in + b_in
  gemm_bt_mfma<true><<<dim3(2048 / 128, MM / 128), blk, 0, stream>>>(
      Xb, WinT, b_in, XGb, 2048);
  // 4. conv + silu -> XCb (bf16)
  conv_silu_k<<<dim3((MM * 128) / 256), blk, 0, stream>>>(XGb, conv_w, conv_b,
                                                          XCb);
  // 5. BC proj (bf16 MFMA): BC = x_conv @ W_x + b_x
  bc_mfma_k<<<dim3(MM / 32), dim3(128), 0, stream>>>(XCb, WxT, b_x, BC);
  // 6. scan phase 1
  scan_local_k<<<dim3(BB, NC, DD / 128), dim3(64), 0, stream>>>(XCb, BC, A_log,
                                                                S);
  // 7. carry + final-state mean
  scan_carry_k<<<dim3((BB * DD * NN) / 256), blk, 0, stream>>>(S, A_log, fs);
  // 8. scan phase 3 -> Y1 bf16
  scan_final_k<<<dim3(BB, NC, DD / 128), dim3(64), 0, stream>>>(
      XCb, XGb, BC, A_log, D_param, S, Y1b);
  // 9. out-proj (bf16 MFMA, f32 out): out = Y1 @ W_out + b_out
  gemm_bt_mfma<false><<<dim3(1024 / 128, MM / 128), blk, 0, stream>>>(
      Y1b, WoutT, b_out, out, 1024);
}

// Round 6
// 278.918 us; speedup vs baseline: 1.1822x; 1.1822x over previous
//
#include <hip/hip_runtime.h>
#include <hip/hip_bf16.h>
#include <math.h>

// Problem constants
#define LL 4096
#define DD 1024
#define NN 16
#define KK 4
#define BB 2
#define MM (BB * LL)   // 8192
#define NC 64          // scan chunks
#define LC 64          // chunk length (NC*LC == LL)

typedef unsigned short ushort_t;
typedef short s16x8 __attribute__((ext_vector_type(8)));
typedef float f32x4 __attribute__((ext_vector_type(4)));
typedef unsigned int u32;

__device__ __forceinline__ ushort_t f2bf(float f) {
  __hip_bfloat16 h = __float2bfloat16(f);
  return *reinterpret_cast<ushort_t*>(&h);
}
__device__ __forceinline__ float bf2f(ushort_t u) {
  union { u32 i; float f; } c;
  c.i = ((u32)u) << 16;
  return c.f;
}

// ---------------------------------------------------------------------------
// bf16 MFMA GEMM, B-transposed: C[M,N] = A[M,K] @ BT[N,K]^T + bias, K=1024.
// 128x128 tile, BK=32, 256 threads (4 waves, 2x2), 16x16x32 MFMA,
// global_load_lds width-16 staging (m97 structure). BF16OUT selects output
// dtype: bf16 for the in-proj intermediate, f32 for the final output.
// ---------------------------------------------------------------------------
template <bool BF16OUT>
__global__ __launch_bounds__(256) void gemm_bt_mfma(
    const ushort_t* __restrict__ A,   // [M,K] bf16
    const ushort_t* __restrict__ BT,  // [N,K] bf16
    const float* __restrict__ bias,
    void* __restrict__ Cv, int N) {
  constexpr int K = 1024;
  __shared__ ushort_t As[128 * 32];
  __shared__ ushort_t Bs[128 * 32];

  const int tid = threadIdx.x;
  const int lane = tid & 63;
  const int w = tid >> 6;            // wave 0..3
  const int wm = w & 1, wn = w >> 1; // 2x2 wave grid over the 128x128 tile
  const int row0 = blockIdx.y * 128;
  const int col0 = blockIdx.x * 128;

  const int lrow = lane >> 2;        // 0..15
  const int lk = (lane & 3) * 8;     // 0,8,16,24

  f32x4 acc[4][4];
#pragma unroll
  for (int i = 0; i < 4; ++i)
#pragma unroll
    for (int j = 0; j < 4; ++j) acc[i][j] = (f32x4){0.f, 0.f, 0.f, 0.f};

  const int frow = lane & 15;
  const int quad = lane >> 4;

  for (int k0 = 0; k0 < K; k0 += 32) {
#pragma unroll
    for (int it = 0; it < 2; ++it) {
      int r = it * 64 + w * 16;
      __builtin_amdgcn_global_load_lds(
          (const __attribute__((address_space(1))) u32*)(A + (size_t)(row0 + r + lrow) * K + k0 + lk),
          (__attribute__((address_space(3))) u32*)(As + r * 32), 16, 0, 0);
      __builtin_amdgcn_global_load_lds(
          (const __attribute__((address_space(1))) u32*)(BT + (size_t)(col0 + r + lrow) * K + k0 + lk),
          (__attribute__((address_space(3))) u32*)(Bs + r * 32), 16, 0, 0);
    }
    __syncthreads();

    s16x8 af[4], bf[4];
#pragma unroll
    for (int mi = 0; mi < 4; ++mi)
      af[mi] = *(const s16x8*)&As[(wm * 64 + mi * 16 + frow) * 32 + quad * 8];
#pragma unroll
    for (int ni = 0; ni < 4; ++ni)
      bf[ni] = *(const s16x8*)&Bs[(wn * 64 + ni * 16 + frow) * 32 + quad * 8];
#pragma unroll
    for (int mi = 0; mi < 4; ++mi)
#pragma unroll
      for (int ni = 0; ni < 4; ++ni)
        acc[mi][ni] = __builtin_amdgcn_mfma_f32_16x16x32_bf16(
            af[mi], bf[ni], acc[mi][ni], 0, 0, 0);
    __syncthreads();
  }

  // Epilogue: C/D layout col=lane&15, row=quad*4+reg
#pragma unroll
  for (int mi = 0; mi < 4; ++mi) {
#pragma unroll
    for (int ni = 0; ni < 4; ++ni) {
      int col = col0 + wn * 64 + ni * 16 + frow;
      float b = bias[col];
#pragma unroll
      for (int r = 0; r < 4; ++r) {
        int row = row0 + wm * 64 + mi * 16 + quad * 4 + r;
        if constexpr (BF16OUT)
          ((ushort_t*)Cv)[(size_t)row * N + col] = f2bf(acc[mi][ni][r] + b);
        else
          ((float*)Cv)[(size_t)row * N + col] = acc[mi][ni][r] + b;
      }
    }
  }
}

// ---------------------------------------------------------------------------
// BC projection, bf16 MFMA: BC[M,32] = XCb[M,1024] @ WxT[32,1024]^T + b_x.
// ---------------------------------------------------------------------------
__global__ __launch_bounds__(128) void bc_mfma_k(
    const ushort_t* __restrict__ A,   // XCb [M,1024]
    const ushort_t* __restrict__ BT,  // WxT [32,1024]
    const float* __restrict__ bias,   // [32]
    float* __restrict__ C) {          // BC [M,32]
  constexpr int K = 1024;
  __shared__ ushort_t As[32 * 32];
  __shared__ ushort_t Bs[32 * 32];

  const int tid = threadIdx.x;
  const int lane = tid & 63;
  const int w = tid >> 6;
  const int row0 = blockIdx.x * 32;
  const int lrow = lane >> 2;
  const int lk = (lane & 3) * 8;
  const int frow = lane & 15;
  const int quad = lane >> 4;

  f32x4 acc[2];
  acc[0] = (f32x4){0.f, 0.f, 0.f, 0.f};
  acc[1] = (f32x4){0.f, 0.f, 0.f, 0.f};

  for (int k0 = 0; k0 < K; k0 += 32) {
    __builtin_amdgcn_global_load_lds(
        (const __attribute__((address_space(1))) u32*)(A + (size_t)(row0 + w * 16 + lrow) * K + k0 + lk),
        (__attribute__((address_space(3))) u32*)(As + (w * 16) * 32), 16, 0, 0);
    __builtin_amdgcn_global_load_lds(
        (const __attribute__((address_space(1))) u32*)(BT + (size_t)(w * 16 + lrow) * K + k0 + lk),
        (__attribute__((address_space(3))) u32*)(Bs + (w * 16) * 32), 16, 0, 0);
    __syncthreads();

    s16x8 af = *(const s16x8*)&As[(w * 16 + frow) * 32 + quad * 8];
    s16x8 bf0 = *(const s16x8*)&Bs[(frow)*32 + quad * 8];
    s16x8 bf1 = *(const s16x8*)&Bs[(16 + frow) * 32 + quad * 8];
    acc[0] = __builtin_amdgcn_mfma_f32_16x16x32_bf16(af, bf0, acc[0], 0, 0, 0);
    acc[1] = __builtin_amdgcn_mfma_f32_16x16x32_bf16(af, bf1, acc[1], 0, 0, 0);
    __syncthreads();
  }

#pragma unroll
  for (int ni = 0; ni < 2; ++ni) {
    int col = ni * 16 + frow;
    float b = bias[col];
#pragma unroll
    for (int r = 0; r < 4; ++r) {
      int row = row0 + w * 16 + quad * 4 + r;
      C[(size_t)row * 32 + col] = acc[ni][r] + b;
    }
  }
}

// ---------------------------------------------------------------------------
// fp32 -> bf16 cast (4 floats/thread) + zero the 32-float final_state region.
// ---------------------------------------------------------------------------
__global__ __launch_bounds__(256) void cast_bf16_k(
    const float* __restrict__ src, ushort_t* __restrict__ dst,
    float* __restrict__ fs) {
  if (blockIdx.x == 0 && threadIdx.x < 32) fs[threadIdx.x] = 0.f;
  int i = blockIdx.x * 256 + threadIdx.x;
  float4 v = ((const float4*)src)[i];
  ushort4 o;
  o.x = f2bf(v.x); o.y = f2bf(v.y); o.z = f2bf(v.z); o.w = f2bf(v.w);
  ((ushort4*)dst)[i] = o;
}

// ---------------------------------------------------------------------------
// All three weight transposes in one launch (z selects the weight).
// W [K,N] fp32 -> WT [N,K] bf16.
// ---------------------------------------------------------------------------
__global__ void transpose_cast3_k(
    const float* __restrict__ W_in, const float* __restrict__ W_out,
    const float* __restrict__ W_x, ushort_t* __restrict__ WinT,
    ushort_t* __restrict__ WoutT, ushort_t* __restrict__ WxT) {
  constexpr int K = 1024;
  const float* W;
  ushort_t* WT;
  int N;
  if (blockIdx.z == 0) {
    W = W_in; WT = WinT; N = 2048;
  } else if (blockIdx.z == 1) {
    if (blockIdx.x >= 32) return;
    W = W_out; WT = WoutT; N = 1024;
  } else {
    if (blockIdx.x >= 1) return;
    W = W_x; WT = WxT; N = 32;
  }
  __shared__ float t[32][33];
  int nb = blockIdx.x * 32, kb = blockIdx.y * 32;
  int tx = threadIdx.x, ty = threadIdx.y;  // (32,8)
#pragma unroll
  for (int i = 0; i < 32; i += 8)
    t[ty + i][tx] = W[(size_t)(kb + ty + i) * N + nb + tx];
  __syncthreads();
#pragma unroll
  for (int i = 0; i < 32; i += 8)
    WT[(size_t)(nb + ty + i) * K + kb + tx] = f2bf(t[tx][ty + i]);
}

// ---------------------------------------------------------------------------
// Depthwise causal conv (left pad K-1) + SiLU, all-bf16 I/O.
// XGb [M,2048] bf16 -> XCb [M,1024] bf16. 8 d per thread, 16B loads/stores.
// conv_w staged in LDS as [d_group][(d%8)*4+k] with ld=33 so per-lane read
// addresses stride 33 -> all 32 banks covered, conflict-free (R5's 32
// scattered global weight loads per thread were the 63us transaction wall).
// ---------------------------------------------------------------------------
__global__ __launch_bounds__(256) void conv_silu_k(
    const ushort_t* __restrict__ XGb, const float* __restrict__ conv_w,
    const float* __restrict__ conv_b, ushort_t* __restrict__ XCb) {
  __shared__ float cw[128 * 33];  // 16.9 KB
  const int tid = threadIdx.x;
  // stage conv_w (1024 float4s == one per d) coalesced
#pragma unroll
  for (int j = 0; j < 4; ++j) {
    int d = tid + j * 256;  // float4 index == d (K==4)
    float4 v = ((const float4*)conv_w)[d];
    float* p = &cw[(d >> 3) * 33 + (d & 7) * 4];
    p[0] = v.x; p[1] = v.y; p[2] = v.z; p[3] = v.w;
  }
  __syncthreads();

  int gid = blockIdx.x * 256 + tid;  // over M*128
  int m = gid >> 7;
  int dg = gid & 127;  // d-group
  int d0 = dg * 8;
  int l = m & (LL - 1);
  const float* w = &cw[dg * 33];

  float4 b0 = ((const float4*)conv_b)[dg * 2];
  float4 b1 = ((const float4*)conv_b)[dg * 2 + 1];
  float acc[8] = {b0.x, b0.y, b0.z, b0.w, b1.x, b1.y, b1.z, b1.w};

#pragma unroll
  for (int k = 0; k < KK; ++k) {
    int li = l + k - (KK - 1);
    if (li < 0) continue;
    s16x8 v = *(const s16x8*)(XGb + (size_t)(m + k - (KK - 1)) * 2048 + d0);
#pragma unroll
    for (int j = 0; j < 8; ++j)
      acc[j] += bf2f((ushort_t)v[j]) * w[j * 4 + k];
  }
  ushort_t o[8];
#pragma unroll
  for (int j = 0; j < 8; ++j) {
    float s = acc[j] / (1.f + __expf(-acc[j]));
    o[j] = f2bf(s);
  }
  *(s16x8*)(XCb + (size_t)m * DD + d0) = *(const s16x8*)o;
}

// ---------------------------------------------------------------------------
// Scan phase 1: per-chunk local scan from h=0; store chunk end-state S.
// Grid (B, NC, D/128); 64 threads, 2 d per thread (u32 xc loads).
// ---------------------------------------------------------------------------
__global__ __launch_bounds__(64) void scan_local_k(
    const ushort_t* __restrict__ XCb, const float* __restrict__ BC,
    const float* __restrict__ A_log, float* __restrict__ S) {
  const int b = blockIdx.x, c = blockIdx.y;
  const int tid = threadIdx.x;
  const int d0 = blockIdx.z * 128 + tid * 2;
  const int t0 = c * LC;
  const size_t rowb = (size_t)b * LL;

  __shared__ float bcs[LC * 32];
  {
    const float4* src = (const float4*)(BC + (rowb + t0) * 32);
    float4* dst = (float4*)bcs;
#pragma unroll
    for (int i = 0; i < 8; ++i) dst[tid + i * 64] = src[tid + i * 64];
  }

  float a0[NN], a1[NN], h0[NN], h1[NN];
#pragma unroll
  for (int n = 0; n < NN; ++n) {
    a0[n] = expf(-expf(A_log[d0 * NN + n]));
    a1[n] = expf(-expf(A_log[(d0 + 1) * NN + n]));
    h0[n] = 0.f;
    h1[n] = 0.f;
  }
  __syncthreads();

  const ushort_t* xp = XCb + (rowb + t0) * DD + d0;
  u32 xw = *(const u32*)xp;
  for (int t = 0; t < LC; ++t) {
    u32 xw_n = (t + 1 < LC) ? *(const u32*)(xp + (size_t)(t + 1) * DD) : 0u;
    float x0 = bf2f((ushort_t)(xw & 0xffff));
    float x1 = bf2f((ushort_t)(xw >> 16));
    const float* bp = bcs + t * 32;
#pragma unroll
    for (int n = 0; n < NN; ++n) {
      float bv = bp[n];
      h0[n] = a0[n] * h0[n] + x0 * bv;
      h1[n] = a1[n] * h1[n] + x1 * bv;
    }
    xw = xw_n;
  }
  float* sp = S + (((size_t)(b * NC + c)) * DD + d0) * NN;
#pragma unroll
  for (int n = 0; n < NN; ++n) sp[n] = h0[n];
#pragma unroll
  for (int n = 0; n < NN; ++n) sp[NN + n] = h1[n];
}

// ---------------------------------------------------------------------------
// Scan phase 2: sequential carry over chunks (S -> H0 in place) + fs mean.
// ---------------------------------------------------------------------------
__global__ __launch_bounds__(256) void scan_carry_k(
    float* __restrict__ S, const float* __restrict__ A_log,
    float* __restrict__ fs) {
  const int idx = blockIdx.x * 256 + threadIdx.x;
  const int n = idx & (NN - 1);
  const int d = (idx / NN) & (DD - 1);
  const int b = idx / (NN * DD);

  const float aLC = expf(-(float)LC * expf(A_log[d * NN + n]));
  float h = 0.f;
  for (int c = 0; c < NC; ++c) {
    size_t off = (((size_t)(b * NC + c)) * DD + d) * NN + n;
    float s = S[off];
    S[off] = h;
    h = aLC * h + s;
  }
  __shared__ float red[256];
  red[threadIdx.x] = h * (1.f / (float)DD);
  __syncthreads();
  if (threadIdx.x < NN) {
    float sum = 0.f;
#pragma unroll
    for (int i = 0; i < 16; ++i) sum += red[i * NN + threadIdx.x];
    atomicAdd(&fs[b * NN + threadIdx.x], sum);
  }
}

// ---------------------------------------------------------------------------
// Scan phase 3: replay from H0, y*silu(gate) -> Y1b bf16. 2 d per thread.
// ---------------------------------------------------------------------------
__global__ __launch_bounds__(64) void scan_final_k(
    const ushort_t* __restrict__ XCb, const ushort_t* __restrict__ XGb,
    const float* __restrict__ BC, const float* __restrict__ A_log,
    const float* __restrict__ D_param, const float* __restrict__ H0,
    ushort_t* __restrict__ Y1b) {
  const int b = blockIdx.x, c = blockIdx.y;
  const int tid = threadIdx.x;
  const int d0 = blockIdx.z * 128 + tid * 2;
  const int t0 = c * LC;
  const size_t rowb = (size_t)b * LL;

  __shared__ float bcs[LC * 32];
  {
    const float4* src = (const float4*)(BC + (rowb + t0) * 32);
    float4* dst = (float4*)bcs;
#pragma unroll
    for (int i = 0; i < 8; ++i) dst[tid + i * 64] = src[tid + i * 64];
  }

  float a0[NN], a1[NN], h0[NN], h1[NN];
  const float* hp = H0 + (((size_t)(b * NC + c)) * DD + d0) * NN;
#pragma unroll
  for (int n = 0; n < NN; ++n) {
    a0[n] = expf(-expf(A_log[d0 * NN + n]));
    a1[n] = expf(-expf(A_log[(d0 + 1) * NN + n]));
    h0[n] = hp[n];
    h1[n] = hp[NN + n];
  }
  const float Dp0 = D_param[d0], Dp1 = D_param[d0 + 1];
  __syncthreads();

  const ushort_t* xp = XCb + (rowb + t0) * DD + d0;
  const ushort_t* gp = XGb + (rowb + t0) * 2048 + DD + d0;
  ushort_t* yp = Y1b + (rowb + t0) * DD + d0;
  u32 xw = *(const u32*)xp;
  u32 gw = *(const u32*)gp;
  for (int t = 0; t < LC; ++t) {
    u32 xw_n = 0u, gw_n = 0u;
    if (t + 1 < LC) {
      xw_n = *(const u32*)(xp + (size_t)(t + 1) * DD);
      gw_n = *(const u32*)(gp + (size_t)(t + 1) * 2048);
    }
    float x0 = bf2f((ushort_t)(xw & 0xffff));
    float x1 = bf2f((ushort_t)(xw >> 16));
    float g0 = bf2f((ushort_t)(gw & 0xffff));
    float g1 = bf2f((ushort_t)(gw >> 16));
    float y0 = Dp0 * x0, y1 = Dp1 * x1;
    const float* bp = bcs + t * 32;
#pragma unroll
    for (int n = 0; n < NN; ++n) {
      float bv = bp[n], cv = bp[16 + n];
      h0[n] = a0[n] * h0[n] + x0 * bv;
      h1[n] = a1[n] * h1[n] + x1 * bv;
      y0 += cv * h0[n];
      y1 += cv * h1[n];
    }
    float sg0 = g0 / (1.f + __expf(-g0));
    float sg1 = g1 / (1.f + __expf(-g1));
    u32 outw = (u32)f2bf(y0 * sg0) | ((u32)f2bf(y1 * sg1) << 16);
    *(u32*)(yp + (size_t)t * DD) = outw;
    xw = xw_n;
    gw = gw_n;
  }
}

// ---------------------------------------------------------------------------
extern "C" void kernel_launch(void* const* d_in, const int* in_sizes, int n_in,
                              void* d_out, int out_size, void* d_ws,
                              size_t ws_size, hipStream_t stream) {
  const float* x = (const float*)d_in[0];
  const float* W_in = (const float*)d_in[1];
  const float* b_in = (const float*)d_in[2];
  const float* conv_w = (const float*)d_in[3];
  const float* conv_b = (const float*)d_in[4];
  const float* W_x = (const float*)d_in[5];
  const float* b_x = (const float*)d_in[6];
  const float* A_log = (const float*)d_in[7];
  const float* D_param = (const float*)d_in[8];
  const float* W_out = (const float*)d_in[9];
  const float* b_out = (const float*)d_in[10];
  float* out = (float*)d_out;
  float* fs = out + (size_t)MM * DD;

  // ws layout: f32 regions then bf16 regions (all 16B-aligned)
  float* BC = (float*)d_ws;                    // [8192*32] f32
  float* S = BC + (size_t)MM * 32;             // [2*64*1024*16] f32
  ushort_t* Xb = (ushort_t*)(S + (size_t)BB * NC * DD * NN);  // [8192*1024]
  ushort_t* XGb = Xb + (size_t)MM * DD;        // [8192*2048] bf16
  ushort_t* XCb = XGb + (size_t)MM * 2048;     // [8192*1024] bf16
  ushort_t* Y1b = XCb + (size_t)MM * DD;       // [8192*1024] bf16
  ushort_t* WinT = Y1b + (size_t)MM * DD;      // [2048*1024] bf16
  ushort_t* WoutT = WinT + (size_t)2048 * DD;  // [1024*1024] bf16
  ushort_t* WxT = WoutT + (size_t)DD * DD;     // [32*1024] bf16

  dim3 blk(256);
  // 1. cast x -> bf16 (+ zero final_state accumulator)
  cast_bf16_k<<<dim3((MM * DD) / 1024), blk, 0, stream>>>(x, Xb, fs);
  // 2. all weight transposes
  transpose_cast3_k<<<dim3(64, 32, 3), dim3(32, 8), 0, stream>>>(
      W_in, W_out, W_x, WinT, WoutT, WxT);
  // 3. in-proj (bf16 MFMA, bf16 out): XGb = x @ W_in + b_in
  gemm_bt_mfma<true><<<dim3(2048 / 128, MM / 128), blk, 0, stream>>>(
      Xb, WinT, b_in, XGb, 2048);
  // 4. conv + silu -> XCb (bf16)
  conv_silu_k<<<dim3((MM * 128) / 256), blk, 0, stream>>>(XGb, conv_w, conv_b,
                                                          XCb);
  // 5. BC proj (bf16 MFMA): BC = x_conv @ W_x + b_x
  bc_mfma_k<<<dim3(MM / 32), dim3(128), 0, stream>>>(XCb, WxT, b_x, BC);
  // 6. scan phase 1
  scan_local_k<<<dim3(BB, NC, DD / 128), dim3(64), 0, stream>>>(XCb, BC, A_log,
                                                                S);
  // 7. carry + final-state mean
  scan_carry_k<<<dim3((BB * DD * NN) / 256), blk, 0, stream>>>(S, A_log, fs);
  // 8. scan phase 3 -> Y1 bf16
  scan_final_k<<<dim3(BB, NC, DD / 128), dim3(64), 0, stream>>>(
      XCb, XGb, BC, A_log, D_param, S, Y1b);
  // 9. out-proj (bf16 MFMA, f32 out): out = Y1 @ W_out + b_out
  gemm_bt_mfma<false><<<dim3(1024 / 128, MM / 128), blk, 0, stream>>>(
      Y1b, WoutT, b_out, out, 1024);
}